// Round 1
// baseline (431.348 us; speedup 1.0000x reference)
//
#include <hip/hip_runtime.h>
#include <cstdint>
#include <cstddef>

typedef __bf16 bf16_t;
typedef __bf16 bf16x8 __attribute__((ext_vector_type(8)));
typedef __bf16 bf16x4v __attribute__((ext_vector_type(4)));
typedef float f32x16 __attribute__((ext_vector_type(16)));

static __device__ __forceinline__ f32x16 mfma32(bf16x8 a, bf16x8 b, f32x16 c) {
  return __builtin_amdgcn_mfma_f32_32x32x16_bf16(a, b, c, 0, 0, 0);
}

// ---------------------------------------------------------------------------
// Workspace layout (bytes):
//   [0, 768K)        Wt   bf16 [3][128][1024]   (W transposed, n-major)
//   [1M, 9M)         Qp   bf16 [8][4096][128]
//   [9M, 17M)        Kp   bf16 [8][4096][128]
//   [17M, 25M)       Vt   bf16 [8][128][4096]   (V projected, d-major)
// ---------------------------------------------------------------------------

__global__ void wt_kernel(const float* __restrict__ Wq, const float* __restrict__ Wk,
                          const float* __restrict__ Wv, bf16_t* __restrict__ Wt) {
  int t = blockIdx.x * 256 + threadIdx.x;   // 0..393215
  int tensor = t >> 17;
  int r = t & 131071;
  int kk = r >> 7, n = r & 127;
  const float* W = tensor == 0 ? Wq : (tensor == 1 ? Wk : Wv);
  Wt[(size_t)tensor * 131072 + (size_t)n * 1024 + kk] = (bf16_t)W[(size_t)kk * 128 + n];
}

// X[32768,1024]f32 @ W[1024,128] -> bf16. ty: 0=Q, 1=K (row-major), 2=V (transposed out).
__global__ __launch_bounds__(256, 2) void proj_kernel(
    const float* __restrict__ xq, const float* __restrict__ xk, const float* __restrict__ xv,
    const bf16_t* __restrict__ WtAll,
    bf16_t* __restrict__ Qp, bf16_t* __restrict__ Kp, bf16_t* __restrict__ Vt) {
  __shared__ uint4 sm[2048];  // 32KB: A-tile [0,8K), W-tile [8K,16K); epilogue transpose [0,32K)
  const int tid = threadIdx.x;
  const int ty = blockIdx.y;
  const int bm = blockIdx.x;      // 0..255 row-blocks of 128
  const float* X = (ty == 0) ? xq : (ty == 1) ? xk : xv;
  const bf16_t* W = WtAll + (size_t)ty * 131072;
  const int lane = tid & 63;
  const int w = tid >> 6;
  const int l31 = lane & 31, h = lane >> 5;
  const int swl = (l31 >> 1) & 3;

  f32x16 acc[4];
#pragma unroll
  for (int nf = 0; nf < 4; ++nf)
#pragma unroll
    for (int r = 0; r < 16; ++r) acc[nf][r] = 0.0f;

  const int arow0 = tid >> 3, afs = tid & 7;   // A chunk: row = arow0+32i, 16B slot afs
  const float* agp = X + (size_t)(bm * 128 + arow0) * 1024 + afs * 4;
  const int wn0 = tid >> 2, wsl = tid & 3;     // W chunk: n = wn0+64i, slot wsl
  const bf16_t* wgp = W + (size_t)wn0 * 1024 + wsl * 8;

  for (int kt = 0; kt < 32; ++kt) {
    const int k0 = kt * 32;
    uint4 av[4];
#pragma unroll
    for (int i = 0; i < 4; ++i) av[i] = *(const uint4*)(agp + (size_t)i * 32 * 1024 + k0);
    uint4 wv2[2];
#pragma unroll
    for (int i = 0; i < 2; ++i) wv2[i] = *(const uint4*)(wgp + (size_t)i * 64 * 1024 + k0);
    __syncthreads();   // previous compute done
#pragma unroll
    for (int i = 0; i < 4; ++i) {
      int row = arow0 + 32 * i;
      float4 f = __builtin_bit_cast(float4, av[i]);
      bf16x4v bv; bv[0] = (bf16_t)f.x; bv[1] = (bf16_t)f.y; bv[2] = (bf16_t)f.z; bv[3] = (bf16_t)f.w;
      int byt = row * 64 + (((afs >> 1) ^ ((row >> 1) & 3)) << 4) + (afs & 1) * 8;
      *(uint2*)((char*)sm + byt) = __builtin_bit_cast(uint2, bv);
    }
#pragma unroll
    for (int i = 0; i < 2; ++i) {
      int n = wn0 + 64 * i;
      int byt = 8192 + n * 64 + ((wsl ^ ((n >> 1) & 3)) << 4);
      *(uint4*)((char*)sm + byt) = wv2[i];
    }
    __syncthreads();
#pragma unroll
    for (int ks = 0; ks < 2; ++ks) {
      const int so = ((2 * ks + h) ^ swl) << 4;
      bf16x8 af = *(const bf16x8*)((const char*)sm + (w * 32 + l31) * 64 + so);
#pragma unroll
      for (int nf = 0; nf < 4; ++nf) {
        bf16x8 wf = *(const bf16x8*)((const char*)sm + 8192 + (nf * 32 + l31) * 64 + so);
        acc[nf] = mfma32(af, wf, acc[nf]);
      }
    }
  }

  const int mbase = bm * 128 + w * 32;
  if (ty < 2) {
    bf16_t* O = (ty == 0) ? Qp : Kp;
#pragma unroll
    for (int nf = 0; nf < 4; ++nf)
#pragma unroll
      for (int r = 0; r < 16; ++r) {
        int rowD = (r & 3) + 8 * (r >> 2) + 4 * h;
        O[(size_t)(mbase + rowD) * 128 + nf * 32 + l31] = (bf16_t)acc[nf][r];
      }
  } else {
    // transpose 128x128 tile through LDS, write Vt[b][n][m] coalesced
    __syncthreads();
#pragma unroll
    for (int nf = 0; nf < 4; ++nf)
#pragma unroll
      for (int rg = 0; rg < 4; ++rg) {
        int n = nf * 32 + l31;
        bf16x4v bv;
#pragma unroll
        for (int j = 0; j < 4; ++j) bv[j] = (bf16_t)acc[nf][rg * 4 + j];
        int byt = n * 256 + (((4 * w + rg) ^ (n & 7)) << 4) + 8 * h;
        *(uint2*)((char*)sm + byt) = __builtin_bit_cast(uint2, bv);
      }
    __syncthreads();
    const int bb = bm >> 5;
    const int r0v = (bm & 31) * 128;
#pragma unroll
    for (int i = 0; i < 8; ++i) {
      int c = tid + 256 * i;          // 2048 chunks of 16B
      int n = c >> 4, sl = c & 15;
      uint4 vv = *(const uint4*)((const char*)sm + n * 256 + ((sl ^ (n & 7)) << 4));
      *(uint4*)(Vt + (size_t)(bb * 128 + n) * 4096 + r0v + sl * 8) = vv;
    }
  }
}

// Flash attention. 128 threads (2 waves), QBLK=64 (32 q-rows/wave), KVBLK=64.
// grid.x = 512: b = bid&7 (XCD affinity), tile = bid>>3.
__global__ __launch_bounds__(128, 2) void attn_kernel(
    const bf16_t* __restrict__ Qp, const bf16_t* __restrict__ Kp,
    const bf16_t* __restrict__ Vt, float* __restrict__ out) {
  __shared__ uint4 sm[2560];  // K [0,16K), V [16K,32K), P per-wave [32K,40K)
  const int tid = threadIdx.x;
  const int lane = tid & 63, w = tid >> 6;
  const int l31 = lane & 31, h = lane >> 5, L7 = lane & 7;
  const int bid = blockIdx.x;
  const int b = bid & 7, tile = bid >> 3;
  const int qbase = tile * 64 + w * 32;
  const float CEXP = 0.08838834764831845f * 1.4426950408889634f;  // 1/sqrt(128)*log2(e)

  // Q fragments (B-operand of swapped QK^T): lane holds q-row l31, d = db*16+h*8..+8
  bf16x8 qf[8];
  const bf16_t* qrow = Qp + (size_t)(b * 4096 + qbase + l31) * 128 + h * 8;
#pragma unroll
  for (int db = 0; db < 8; ++db) qf[db] = *(const bf16x8*)(qrow + db * 16);

  const char* kg = (const char*)Kp + (size_t)b * 1048576 + (tid >> 4) * 256 + (tid & 15) * 16;
  const char* vg = (const char*)Vt + (size_t)b * 1048576 + (tid >> 3) * 8192 + (tid & 7) * 16;
  const int kwb = (tid >> 4) * 256 + (((tid & 15) ^ ((tid >> 4) & 7)) << 4);
  const int vwb = 16384 + (tid >> 3) * 128 + (((tid & 7) ^ ((tid >> 3) & 7)) << 4);
  const int pbase = 32768 + w * 4096 + l31 * 128;

  f32x16 oacc[4];
#pragma unroll
  for (int nf = 0; nf < 4; ++nf)
#pragma unroll
    for (int r = 0; r < 16; ++r) oacc[nf][r] = 0.0f;
  float m_run = -3.0e38f, lacc = 0.0f;

  for (int t = 0; t < 64; ++t) {
    // ---- stage K tile [64][128] and Vt tile [128][64] into swizzled LDS ----
    uint4 kv[8], vv[8];
#pragma unroll
    for (int i = 0; i < 8; ++i) kv[i] = *(const uint4*)(kg + (size_t)t * 16384 + i * 2048);
#pragma unroll
    for (int i = 0; i < 8; ++i) vv[i] = *(const uint4*)(vg + (size_t)t * 128 + (size_t)i * 131072);
    __syncthreads();
#pragma unroll
    for (int i = 0; i < 8; ++i) *(uint4*)((char*)sm + kwb + i * 2048) = kv[i];
#pragma unroll
    for (int i = 0; i < 8; ++i) *(uint4*)((char*)sm + vwb + i * 2048) = vv[i];
    __syncthreads();

    // ---- S^T = mfma(K, Q): lane owns q-row l31; j = jf*32 + (reg&3)+8*(reg>>2)+4h ----
    f32x16 s0, s1;
#pragma unroll
    for (int i = 0; i < 16; ++i) { s0[i] = 0.0f; s1[i] = 0.0f; }
#pragma unroll
    for (int db = 0; db < 8; ++db) {
      const int so = ((2 * db + h) ^ L7) << 4;
      bf16x8 k0 = *(const bf16x8*)((const char*)sm + l31 * 256 + so);
      bf16x8 k1 = *(const bf16x8*)((const char*)sm + (32 + l31) * 256 + so);
      s0 = mfma32(k0, qf[db], s0);
      s1 = mfma32(k1, qf[db], s1);
    }

    // ---- online softmax (raw logits; scale folded into exp2 constant) ----
    float tmax = fmaxf(s0[0], s1[0]);
#pragma unroll
    for (int i = 1; i < 16; ++i) tmax = fmaxf(tmax, fmaxf(s0[i], s1[i]));
    tmax = fmaxf(tmax, __shfl_xor(tmax, 32));
    if (__any(tmax > m_run + 62.0f)) {   // defer-max: p bounded by 2^7.9
      float mnew = fmaxf(m_run, tmax);
      float fac = exp2f((m_run - mnew) * CEXP);
      m_run = mnew;
      lacc *= fac;
#pragma unroll
      for (int r = 0; r < 16; ++r) {
        float fr = __shfl(fac, (r & 3) + 8 * (r >> 2) + 4 * h);
#pragma unroll
        for (int nf = 0; nf < 4; ++nf) oacc[nf][r] *= fr;
      }
    }
    const float mc = m_run * CEXP;
#pragma unroll
    for (int i = 0; i < 16; ++i) s0[i] = exp2f(fmaf(s0[i], CEXP, -mc));
#pragma unroll
    for (int i = 0; i < 16; ++i) s1[i] = exp2f(fmaf(s1[i], CEXP, -mc));
    float a0 = 0.f, a1 = 0.f, a2 = 0.f, a3 = 0.f;
#pragma unroll
    for (int i = 0; i < 16; i += 4) {
      a0 += s0[i] + s1[i];     a1 += s0[i + 1] + s1[i + 1];
      a2 += s0[i + 2] + s1[i + 2]; a3 += s0[i + 3] + s1[i + 3];
    }
    lacc += (a0 + a1) + (a2 + a3);

    // ---- P -> bf16 -> wave-private swizzled LDS (A-layout for PV) ----
#pragma unroll
    for (int rg = 0; rg < 4; ++rg) {
      bf16x4v p0, p1;
#pragma unroll
      for (int j = 0; j < 4; ++j) { p0[j] = (bf16_t)s0[rg * 4 + j]; p1[j] = (bf16_t)s1[rg * 4 + j]; }
      *(uint2*)((char*)sm + pbase + ((rg ^ L7) << 4) + 8 * h) = __builtin_bit_cast(uint2, p0);
      *(uint2*)((char*)sm + pbase + (((4 + rg) ^ L7) << 4) + 8 * h) = __builtin_bit_cast(uint2, p1);
    }
    asm volatile("" ::: "memory");  // order P writes before P reads (wave-private)

    // ---- PV: out += P[32q x 64j] @ V[64j x 128n] ----
#pragma unroll
    for (int js = 0; js < 4; ++js) {
      const int so = ((2 * js + h) ^ L7) << 4;
      bf16x8 pf = *(const bf16x8*)((const char*)sm + pbase + so);
#pragma unroll
      for (int nf = 0; nf < 4; ++nf) {
        bf16x8 vf = *(const bf16x8*)((const char*)sm + 16384 + (nf * 32 + l31) * 128 + so);
        oacc[nf] = mfma32(pf, vf, oacc[nf]);
      }
    }
  }

  // ---- epilogue: normalize and store f32 ----
  lacc += __shfl_xor(lacc, 32);
  const float inv = 1.0f / lacc;
  float* ob = out + (size_t)(b * 4096 + qbase) * 128;
#pragma unroll
  for (int r = 0; r < 16; ++r) {
    const int rowD = (r & 3) + 8 * (r >> 2) + 4 * h;
    float ir = __shfl(inv, rowD);
#pragma unroll
    for (int nf = 0; nf < 4; ++nf)
      ob[(size_t)rowD * 128 + nf * 32 + l31] = oacc[nf][r] * ir;
  }
}

extern "C" void kernel_launch(void* const* d_in, const int* in_sizes, int n_in,
                              void* d_out, int out_size, void* d_ws, size_t ws_size,
                              hipStream_t stream) {
  const float* q  = (const float*)d_in[0];
  const float* k  = (const float*)d_in[1];
  const float* v  = (const float*)d_in[2];
  const float* Wq = (const float*)d_in[3];
  const float* Wk = (const float*)d_in[4];
  const float* Wv = (const float*)d_in[5];
  float* out = (float*)d_out;
  char* ws = (char*)d_ws;
  bf16_t* Wt = (bf16_t*)(ws);
  bf16_t* Qp = (bf16_t*)(ws + (size_t)(1u << 20));
  bf16_t* Kp = (bf16_t*)(ws + (size_t)(9u << 20));
  bf16_t* Vt = (bf16_t*)(ws + (size_t)(17u << 20));

  hipLaunchKernelGGL(wt_kernel, dim3(1536), dim3(256), 0, stream, Wq, Wk, Wv, Wt);
  hipLaunchKernelGGL(proj_kernel, dim3(256, 3), dim3(256), 0, stream, q, k, v, Wt, Qp, Kp, Vt);
  hipLaunchKernelGGL(attn_kernel, dim3(512), dim3(128), 0, stream, Qp, Kp, Vt, out);
}